// Round 1
// baseline (270.189 us; speedup 1.0000x reference)
//
#include <hip/hip_runtime.h>

#define B_N 16384
#define H_N 256
#define FEAT_N 256
#define IN_W 258
#define GX_N 70
#define GY_N 70
#define SW_N 2
#define KK_N 25

typedef __bf16 bf16x8 __attribute__((ext_vector_type(8)));
typedef __bf16 bf16x4 __attribute__((ext_vector_type(4)));
typedef float f32x4 __attribute__((ext_vector_type(4)));

// ---- ws layout (bytes) ----
// 0         : featB  bf16 [16384*256]   (later overwritten by combB bf16 [16384*512])
// 8388608   : hidB   bf16 [16384*256]
// 16777216  : wihB   bf16 [1024*256]
// 17301504  : whhB   bf16 [1024*256]
// 17825792  : woutB  bf16 [256*512]
// 18087936  : ng     f32  [16384*256]
// 34865152  : ug     f32  [16384*256]
// 51642368  : sg     f32  [16384*256]
// total 68419584 bytes

// region boundaries in bf16 elements for the cast kernel
#define E_FEAT 4194304ULL
#define E_HID  8388608ULL
#define E_WIH  8650752ULL
#define E_WHH  8912896ULL
#define E_END  9043968ULL

__global__ __launch_bounds__(256) void cast_kernel(
    const float* __restrict__ in_t, const float* __restrict__ hid,
    const float* __restrict__ wih, const float* __restrict__ whh,
    const float* __restrict__ wout, __bf16* __restrict__ dst)
{
    size_t g = (size_t)blockIdx.x * blockDim.x + threadIdx.x;
    size_t stride = (size_t)gridDim.x * blockDim.x;
    for (size_t e = g * 4; e < E_END; e += stride * 4) {
        const float* src;
        if (e < E_FEAT) {
            size_t row = e >> 8;
            src = in_t + row * IN_W + (e & 255);
        } else if (e < E_HID) {
            src = hid + (e - E_FEAT);
        } else if (e < E_WIH) {
            src = wih + (e - E_HID);
        } else if (e < E_WHH) {
            src = whh + (e - E_WIH);
        } else {
            src = wout + (e - E_WHH);
        }
        bf16x4 o;
        o.x = (__bf16)src[0];
        o.y = (__bf16)src[1];
        o.z = (__bf16)src[2];
        o.w = (__bf16)src[3];
        *reinterpret_cast<bf16x4*>(dst + e) = o;
    }
}

// Fused gi/gh GEMM + gate epilogue.
// grid = (16 h-tiles of 16 cols, 128 row-tiles of 128 rows), block = 256 (4 waves)
// wave handles 32 rows x 16 cols, accumulating 4 gi-chunks and 4 gh-chunks.
__global__ __launch_bounds__(256) void gates_gemm(
    const __bf16* __restrict__ featB, const __bf16* __restrict__ hidB,
    const __bf16* __restrict__ wihB, const __bf16* __restrict__ whhB,
    const float* __restrict__ b_ih, const float* __restrict__ b_hh,
    float* __restrict__ ng, float* __restrict__ ug, float* __restrict__ sg)
{
    const int wave = threadIdx.x >> 6;
    const int lane = threadIdx.x & 63;
    const int h0 = blockIdx.x * 16;
    const int r0 = blockIdx.y * 128 + wave * 32;
    const int lr = lane & 15;
    const int lk = (lane >> 4) * 8;

    f32x4 acc_i[2][4], acc_h[2][4];
    for (int m = 0; m < 2; m++)
        for (int c = 0; c < 4; c++) {
            acc_i[m][c] = (f32x4){0.f, 0.f, 0.f, 0.f};
            acc_h[m][c] = (f32x4){0.f, 0.f, 0.f, 0.f};
        }

    const __bf16* fA0 = featB + (size_t)(r0 + lr) * FEAT_N + lk;
    const __bf16* fA1 = featB + (size_t)(r0 + 16 + lr) * FEAT_N + lk;
    const __bf16* hA0 = hidB + (size_t)(r0 + lr) * H_N + lk;
    const __bf16* hA1 = hidB + (size_t)(r0 + 16 + lr) * H_N + lk;

    for (int kt = 0; kt < FEAT_N; kt += 32) {
        bf16x8 af0 = *reinterpret_cast<const bf16x8*>(fA0 + kt);
        bf16x8 af1 = *reinterpret_cast<const bf16x8*>(fA1 + kt);
        bf16x8 ah0 = *reinterpret_cast<const bf16x8*>(hA0 + kt);
        bf16x8 ah1 = *reinterpret_cast<const bf16x8*>(hA1 + kt);
#pragma unroll
        for (int c = 0; c < 4; c++) {
            int n = h0 + 256 * c + lr;
            bf16x8 bi = *reinterpret_cast<const bf16x8*>(wihB + (size_t)n * FEAT_N + kt + lk);
            bf16x8 bh = *reinterpret_cast<const bf16x8*>(whhB + (size_t)n * H_N + kt + lk);
            acc_i[0][c] = __builtin_amdgcn_mfma_f32_16x16x32_bf16(af0, bi, acc_i[0][c], 0, 0, 0);
            acc_i[1][c] = __builtin_amdgcn_mfma_f32_16x16x32_bf16(af1, bi, acc_i[1][c], 0, 0, 0);
            acc_h[0][c] = __builtin_amdgcn_mfma_f32_16x16x32_bf16(ah0, bh, acc_h[0][c], 0, 0, 0);
            acc_h[1][c] = __builtin_amdgcn_mfma_f32_16x16x32_bf16(ah1, bh, acc_h[1][c], 0, 0, 0);
        }
    }

    const int col = h0 + lr;
    const float bir = b_ih[col], bhr = b_hh[col];
    const float bii = b_ih[col + 256], bhi = b_hh[col + 256];
    const float bin = b_ih[col + 512], bhn = b_hh[col + 512];
    const float bis = b_ih[col + 768], bhs = b_hh[col + 768];
#pragma unroll
    for (int m = 0; m < 2; m++) {
#pragma unroll
        for (int r = 0; r < 4; r++) {
            int row = r0 + m * 16 + (lane >> 4) * 4 + r;
            float gir = acc_i[m][0][r] + bir, ghr = acc_h[m][0][r] + bhr;
            float gii = acc_i[m][1][r] + bii, ghi = acc_h[m][1][r] + bhi;
            float gin = acc_i[m][2][r] + bin, ghn = acc_h[m][2][r] + bhn;
            float gis = acc_i[m][3][r] + bis, ghs = acc_h[m][3][r] + bhs;
            float rg = 1.f / (1.f + __expf(-(gir + ghr)));
            float ugv = 1.f / (1.f + __expf(-(gii + ghi)));
            float sgv = 1.f / (1.f + __expf(-(gis + ghs)));
            float ngv = tanhf(gin + rg * ghn);
            size_t idx = (size_t)row * H_N + col;
            ng[idx] = ngv;
            ug[idx] = ugv;
            sg[idx] = sgv;
        }
    }
}

// Attention: one wave per batch row.
__global__ __launch_bounds__(256) void attn_kernel(
    const float* __restrict__ in_t, const float* __restrict__ memory,
    const float* __restrict__ ng, __bf16* __restrict__ comb)
{
    const int wave = threadIdx.x >> 6;
    const int lane = threadIdx.x & 63;
    const int b = blockIdx.x * 4 + wave;
    const float* row_in = in_t + (size_t)b * IN_W;
    int gx = (int)row_in[256] + SW_N;
    int gy = (int)row_in[257] + SW_N;
    gx = min(max(gx, 0), GX_N - 1);
    gy = min(max(gy, 0), GY_N - 1);

    float q[4];
#pragma unroll
    for (int t = 0; t < 4; t++) q[t] = ng[(size_t)b * H_N + t * 64 + lane];

    float ctx[KK_N][4];
    float attn[KK_N];
#pragma unroll
    for (int k = 0; k < KK_N; k++) {
        int i = k / 5, j = k % 5;
        int xi = min(max(gx + i - SW_N, 0), GX_N - 1);
        int yj = min(max(gy + j - SW_N, 0), GY_N - 1);
        const float* cp = memory + ((size_t)xi * GY_N + yj) * H_N;
        float p = 0.f;
#pragma unroll
        for (int t = 0; t < 4; t++) {
            float v = cp[t * 64 + lane];
            ctx[k][t] = v;
            p += q[t] * v;
        }
        for (int off = 32; off; off >>= 1) p += __shfl_xor(p, off, 64);
        attn[k] = p;
    }

    float mval = -INFINITY;
#pragma unroll
    for (int k = 0; k < KK_N; k++) {
        float a = (attn[k] == 0.f) ? -INFINITY : attn[k];
        attn[k] = a;
        mval = fmaxf(mval, a);
    }
    float mix[4] = {0.f, 0.f, 0.f, 0.f};
    if (mval != -INFINITY) {
        float den = 0.f;
#pragma unroll
        for (int k = 0; k < KK_N; k++) {
            float e = __expf(attn[k] - mval);
            attn[k] = e;
            den += e;
        }
        float inv = 1.f / den;
#pragma unroll
        for (int k = 0; k < KK_N; k++) {
            float w = attn[k] * inv;
#pragma unroll
            for (int t = 0; t < 4; t++) mix[t] += w * ctx[k][t];
        }
    }
    __bf16* outrow = comb + (size_t)b * 512;
#pragma unroll
    for (int t = 0; t < 4; t++) {
        outrow[t * 64 + lane] = (__bf16)mix[t];
        outrow[256 + t * 64 + lane] = (__bf16)q[t];
    }
}

// Output GEMM (K=512) + tanh + final blend.
// grid = (4 n-tiles of 64, 128 row-tiles of 128), block = 256 (4 waves)
__global__ __launch_bounds__(256) void out_gemm(
    const __bf16* __restrict__ comb, const __bf16* __restrict__ woB,
    const float* __restrict__ b_out, const float* __restrict__ ng,
    const float* __restrict__ ug, const float* __restrict__ sg,
    const float* __restrict__ hidden, float* __restrict__ out)
{
    const int wave = threadIdx.x >> 6;
    const int lane = threadIdx.x & 63;
    const int n0 = blockIdx.x * 64;
    const int r0 = blockIdx.y * 128 + wave * 32;
    const int lr = lane & 15;
    const int lk = (lane >> 4) * 8;

    f32x4 acc[2][4];
    for (int m = 0; m < 2; m++)
        for (int f = 0; f < 4; f++) acc[m][f] = (f32x4){0.f, 0.f, 0.f, 0.f};

    const __bf16* a0p = comb + (size_t)(r0 + lr) * 512 + lk;
    const __bf16* a1p = comb + (size_t)(r0 + 16 + lr) * 512 + lk;

    for (int kt = 0; kt < 512; kt += 32) {
        bf16x8 a0 = *reinterpret_cast<const bf16x8*>(a0p + kt);
        bf16x8 a1 = *reinterpret_cast<const bf16x8*>(a1p + kt);
#pragma unroll
        for (int f = 0; f < 4; f++) {
            bf16x8 bb = *reinterpret_cast<const bf16x8*>(woB + (size_t)(n0 + f * 16 + lr) * 512 + kt + lk);
            acc[0][f] = __builtin_amdgcn_mfma_f32_16x16x32_bf16(a0, bb, acc[0][f], 0, 0, 0);
            acc[1][f] = __builtin_amdgcn_mfma_f32_16x16x32_bf16(a1, bb, acc[1][f], 0, 0, 0);
        }
    }

#pragma unroll
    for (int m = 0; m < 2; m++) {
#pragma unroll
        for (int f = 0; f < 4; f++) {
            int col = n0 + f * 16 + lr;
            float bo = b_out[col];
#pragma unroll
            for (int r = 0; r < 4; r++) {
                int row = r0 + m * 16 + (lane >> 4) * 4 + r;
                size_t idx = (size_t)row * H_N + col;
                float acs = tanhf(acc[m][f][r] + bo);
                float ngv = ng[idx], sgv = sg[idx], ugv = ug[idx], hv = hidden[idx];
                float curr = ngv + sgv * acs;
                out[idx] = curr + ugv * (hv - curr);
            }
        }
    }
}

extern "C" void kernel_launch(void* const* d_in, const int* in_sizes, int n_in,
                              void* d_out, int out_size, void* d_ws, size_t ws_size,
                              hipStream_t stream) {
    const float* input_t = (const float*)d_in[0];
    const float* hidden  = (const float*)d_in[1];
    const float* w_ih    = (const float*)d_in[2];
    const float* b_ih    = (const float*)d_in[3];
    const float* w_hh    = (const float*)d_in[4];
    const float* b_hh    = (const float*)d_in[5];
    const float* w_out   = (const float*)d_in[6];
    const float* b_out   = (const float*)d_in[7];
    const float* memory  = (const float*)d_in[8];
    float* out = (float*)d_out;

    char* ws = (char*)d_ws;
    __bf16* bfbase = (__bf16*)ws;
    __bf16* featB = bfbase;
    __bf16* hidB  = bfbase + E_FEAT;
    __bf16* wihB  = bfbase + E_HID;
    __bf16* whhB  = bfbase + E_WIH;
    __bf16* woutB = bfbase + E_WHH;
    __bf16* combB = bfbase;  // overlaps featB/hidB (both dead by then)
    float* ng = (float*)(ws + 18087936);
    float* ug = ng + 4194304;
    float* sg = ug + 4194304;

    cast_kernel<<<2048, 256, 0, stream>>>(input_t, hidden, w_ih, w_hh, w_out, bfbase);
    gates_gemm<<<dim3(16, 128), 256, 0, stream>>>(featB, hidB, wihB, whhB, b_ih, b_hh, ng, ug, sg);
    attn_kernel<<<4096, 256, 0, stream>>>(input_t, memory, ng, combB);
    out_gemm<<<dim3(4, 128), 256, 0, stream>>>(combB, woutB, b_out, ng, ug, sg, hidden, out);
}

// Round 2
// 217.095 us; speedup vs baseline: 1.2446x; 1.2446x over previous
//
#include <hip/hip_runtime.h>
#include <stdint.h>

#define B_N 16384
#define H_N 256
#define IN_W 258
#define GX_N 70
#define GY_N 70
#define SW_N 2
#define KK_N 25

typedef __bf16 bf16x8 __attribute__((ext_vector_type(8)));
typedef __bf16 bf16x4 __attribute__((ext_vector_type(4)));
typedef __bf16 bf16x2 __attribute__((ext_vector_type(2)));
typedef float f32x4 __attribute__((ext_vector_type(4)));

#define AS1 __attribute__((address_space(1)))
#define AS3 __attribute__((address_space(3)))

static __device__ __forceinline__ void gload16(const void* g, void* l) {
    __builtin_amdgcn_global_load_lds((const AS1 uint32_t*)g, (AS3 uint32_t*)l, 16, 0, 0);
}

// ---- ws layout (bf16 elements unless noted) ----
// AB    at 0        : [16384][512]  ([feat|hid])            16 MB
// wihB  at 8388608  : [1024][256]                           0.5 MB
// whhB  at 8650752  : [1024][256]                           0.5 MB
// woutB at 8912896  : [256][512]                            0.25 MB
// comb  at 9043968  : [16384][512]  ([mix|q])               16 MB
// ugsg  at 17432576 : [16384][256][2] (ug,sg interleaved)   16 MB
#define E_AB   8388608ULL
#define E_WIH  8650752ULL
#define E_WHH  8912896ULL
#define E_WOUT 9043968ULL
#define E_COMB 9043968ULL
#define E_UGSG 17432576ULL

__global__ __launch_bounds__(256) void cast_kernel(
    const float* __restrict__ in_t, const float* __restrict__ hid,
    const float* __restrict__ wih, const float* __restrict__ whh,
    const float* __restrict__ wout, __bf16* __restrict__ dst)
{
    size_t g = (size_t)blockIdx.x * blockDim.x + threadIdx.x;
    size_t stride = (size_t)gridDim.x * blockDim.x;
    for (size_t e = g * 4; e < E_WOUT; e += stride * 4) {
        const float* src;
        if (e < E_AB) {
            size_t row = e >> 9;
            size_t c = e & 511;
            src = (c < 256) ? (in_t + row * IN_W + c) : (hid + row * 256 + (c - 256));
        } else if (e < E_WIH) {
            src = wih + (e - E_AB);
        } else if (e < E_WHH) {
            src = whh + (e - E_WIH);
        } else {
            src = wout + (e - E_WHH);
        }
        bf16x4 o;
        o.x = (__bf16)src[0];
        o.y = (__bf16)src[1];
        o.z = (__bf16)src[2];
        o.w = (__bf16)src[3];
        *reinterpret_cast<bf16x4*>(dst + e) = o;
    }
}

// Fused gates GEMM: block = 128 rows x 32 hcols; computes gi (feat@wihT) and
// gh (hid@whhT) tiles of 128x128 each (4 chunks x 32 cols), LDS-staged with
// global_load_lds (seg-major layout -> conflict-free ds_read_b128).
// Epilogue: gates -> q (bf16 into comb) + ug/sg (bf16x2).
__global__ __launch_bounds__(256, 2) void gates_gemm(
    const __bf16* __restrict__ AB, const __bf16* __restrict__ wihB,
    const __bf16* __restrict__ whhB, const float* __restrict__ b_ih,
    const float* __restrict__ b_hh, __bf16* __restrict__ comb,
    __bf16* __restrict__ ugsg)
{
    __shared__ __bf16 ldsAf[4096], ldsAh[4096], ldsBi[4096], ldsBh[4096];
    const int t = threadIdx.x;
    const int lane = t & 63, w = t >> 6;
    const int lr = lane & 15, seg = lane >> 4;
    const int h0 = blockIdx.x * 32;
    const int rb = blockIdx.y * 128;

    // staging: slot u in [0,512): seg_s = u>>7, row = u&127; thread t owns
    // slots t (seg s_lo) and t+256 (seg s_lo+2 == +16 elems in global k)
    const int r_s = t & 127;
    const int s_lo = t >> 7;
    const __bf16* gAf = AB + (size_t)(rb + r_s) * 512 + s_lo * 8;
    const __bf16* gAh = gAf + 256;
    const int wr = ((r_s >> 5) << 8) + h0 + (r_s & 31);
    const __bf16* gBi = wihB + (size_t)wr * 256 + s_lo * 8;
    const __bf16* gBh = whhB + (size_t)wr * 256 + s_lo * 8;
    __bf16* lAf = ldsAf + t * 8;
    __bf16* lAh = ldsAh + t * 8;
    __bf16* lBi = ldsBi + t * 8;
    __bf16* lBh = ldsBh + t * 8;

    f32x4 acc_i[2][4][2], acc_h[2][4][2];  // [rowhalf][chunk][colhalf]
#pragma unroll
    for (int rh = 0; rh < 2; rh++)
#pragma unroll
        for (int c = 0; c < 4; c++)
#pragma unroll
            for (int hh = 0; hh < 2; hh++) {
                acc_i[rh][c][hh] = (f32x4){0.f, 0.f, 0.f, 0.f};
                acc_h[rh][c][hh] = (f32x4){0.f, 0.f, 0.f, 0.f};
            }

    for (int kt = 0; kt < 256; kt += 32) {
        gload16(gAf + kt, lAf);       gload16(gAf + kt + 16, lAf + 2048);
        gload16(gAh + kt, lAh);       gload16(gAh + kt + 16, lAh + 2048);
        gload16(gBi + kt, lBi);       gload16(gBi + kt + 16, lBi + 2048);
        gload16(gBh + kt, lBh);       gload16(gBh + kt + 16, lBh + 2048);
        __syncthreads();

        bf16x8 af[2], ah[2];
#pragma unroll
        for (int rh = 0; rh < 2; rh++) {
            int tr = w * 32 + rh * 16 + lr;
            af[rh] = *reinterpret_cast<const bf16x8*>(ldsAf + seg * 1024 + tr * 8);
            ah[rh] = *reinterpret_cast<const bf16x8*>(ldsAh + seg * 1024 + tr * 8);
        }
#pragma unroll
        for (int c = 0; c < 4; c++)
#pragma unroll
            for (int hh = 0; hh < 2; hh++) {
                int br = c * 32 + hh * 16 + lr;
                bf16x8 bi = *reinterpret_cast<const bf16x8*>(ldsBi + seg * 1024 + br * 8);
                bf16x8 bh = *reinterpret_cast<const bf16x8*>(ldsBh + seg * 1024 + br * 8);
#pragma unroll
                for (int rh = 0; rh < 2; rh++) {
                    acc_i[rh][c][hh] = __builtin_amdgcn_mfma_f32_16x16x32_bf16(af[rh], bi, acc_i[rh][c][hh], 0, 0, 0);
                    acc_h[rh][c][hh] = __builtin_amdgcn_mfma_f32_16x16x32_bf16(ah[rh], bh, acc_h[rh][c][hh], 0, 0, 0);
                }
            }
        __syncthreads();
    }

#pragma unroll
    for (int hh = 0; hh < 2; hh++) {
        int col = h0 + hh * 16 + lr;
        float b0i = b_ih[col],       b0h = b_hh[col];
        float b1i = b_ih[col + 256], b1h = b_hh[col + 256];
        float b2i = b_ih[col + 512], b2h = b_hh[col + 512];
        float b3i = b_ih[col + 768], b3h = b_hh[col + 768];
#pragma unroll
        for (int rh = 0; rh < 2; rh++) {
#pragma unroll
            for (int r = 0; r < 4; r++) {
                int row = rb + w * 32 + rh * 16 + seg * 4 + r;
                float gir = acc_i[rh][0][hh][r] + b0i, ghr = acc_h[rh][0][hh][r] + b0h;
                float gii = acc_i[rh][1][hh][r] + b1i, ghi = acc_h[rh][1][hh][r] + b1h;
                float gin = acc_i[rh][2][hh][r] + b2i, ghn = acc_h[rh][2][hh][r] + b2h;
                float gis = acc_i[rh][3][hh][r] + b3i, ghs = acc_h[rh][3][hh][r] + b3h;
                float rg = 1.f / (1.f + __expf(-(gir + ghr)));
                float ug = 1.f / (1.f + __expf(-(gii + ghi)));
                float sg = 1.f / (1.f + __expf(-(gis + ghs)));
                float ng = tanhf(gin + rg * ghn);
                size_t idx = (size_t)row * 256 + col;
                comb[(size_t)row * 512 + 256 + col] = (__bf16)ng;
                bf16x2 us;
                us.x = (__bf16)ug;
                us.y = (__bf16)sg;
                *reinterpret_cast<bf16x2*>(ugsg + idx * 2) = us;
            }
        }
    }
}

// Attention: one wave per batch row; q read from comb's q-half (bf16),
// mix written to comb's mix-half (bf16).
__global__ __launch_bounds__(256) void attn_kernel(
    const float* __restrict__ in_t, const float* __restrict__ memory,
    __bf16* __restrict__ comb)
{
    const int w = threadIdx.x >> 6;
    const int lane = threadIdx.x & 63;
    const int b = blockIdx.x * 4 + w;
    const float* row_in = in_t + (size_t)b * IN_W;
    int gx = (int)row_in[256] + SW_N;
    int gy = (int)row_in[257] + SW_N;
    gx = min(max(gx, 0), GX_N - 1);
    gy = min(max(gy, 0), GY_N - 1);

    float q[4];
#pragma unroll
    for (int t4 = 0; t4 < 4; t4++)
        q[t4] = (float)comb[(size_t)b * 512 + 256 + t4 * 64 + lane];

    float ctx[KK_N][4];
    float attn[KK_N];
#pragma unroll
    for (int k = 0; k < KK_N; k++) {
        int i = k / 5, j = k % 5;
        int xi = min(max(gx + i - SW_N, 0), GX_N - 1);
        int yj = min(max(gy + j - SW_N, 0), GY_N - 1);
        const float* cp = memory + ((size_t)xi * GY_N + yj) * H_N;
        float p = 0.f;
#pragma unroll
        for (int t4 = 0; t4 < 4; t4++) {
            float v = cp[t4 * 64 + lane];
            ctx[k][t4] = v;
            p += q[t4] * v;
        }
        for (int off = 32; off; off >>= 1) p += __shfl_xor(p, off, 64);
        attn[k] = p;
    }

    float mval = -INFINITY;
#pragma unroll
    for (int k = 0; k < KK_N; k++) {
        float a = (attn[k] == 0.f) ? -INFINITY : attn[k];
        attn[k] = a;
        mval = fmaxf(mval, a);
    }
    float mix[4] = {0.f, 0.f, 0.f, 0.f};
    if (mval != -INFINITY) {
        float den = 0.f;
#pragma unroll
        for (int k = 0; k < KK_N; k++) {
            float e = __expf(attn[k] - mval);
            attn[k] = e;
            den += e;
        }
        float inv = 1.f / den;
#pragma unroll
        for (int k = 0; k < KK_N; k++) {
            float wk = attn[k] * inv;
#pragma unroll
            for (int t4 = 0; t4 < 4; t4++) mix[t4] += wk * ctx[k][t4];
        }
    }
    __bf16* outrow = comb + (size_t)b * 512;
#pragma unroll
    for (int t4 = 0; t4 < 4; t4++)
        outrow[t4 * 64 + lane] = (__bf16)mix[t4];
}

// Output GEMM (K=512, A=comb, B=woutB) + tanh + final blend.
// block = 128 rows x 64 cols; grid (4, 128).
__global__ __launch_bounds__(256, 4) void out_gemm(
    const __bf16* __restrict__ comb, const __bf16* __restrict__ woB,
    const float* __restrict__ b_out, const __bf16* __restrict__ ugsg,
    const float* __restrict__ hidden, float* __restrict__ out)
{
    __shared__ __bf16 ldsA[4096], ldsB[2048];
    const int t = threadIdx.x;
    const int lane = t & 63, w = t >> 6;
    const int lr = lane & 15, seg = lane >> 4;
    const int n0 = blockIdx.x * 64;
    const int rb = blockIdx.y * 128;

    // A staging: 512 slots seg-major (seg = u>>7, row = u&127)
    const int rA = t & 127;
    const int sA = t >> 7;
    const __bf16* gA = comb + (size_t)(rb + rA) * 512 + sA * 8;
    __bf16* lA = ldsA + t * 8;
    // B staging: 256 slots (seg = u>>6 in 0..3, row = u&63)
    const __bf16* gB = woB + (size_t)(n0 + (t & 63)) * 512 + (t >> 6) * 8;
    __bf16* lB = ldsB + t * 8;

    f32x4 acc[2][4];  // [rowhalf][coltile]
#pragma unroll
    for (int rh = 0; rh < 2; rh++)
#pragma unroll
        for (int ct = 0; ct < 4; ct++) acc[rh][ct] = (f32x4){0.f, 0.f, 0.f, 0.f};

    for (int kt = 0; kt < 512; kt += 32) {
        gload16(gA + kt, lA);
        gload16(gA + kt + 16, lA + 2048);
        gload16(gB + kt, lB);
        __syncthreads();

        bf16x8 af[2];
#pragma unroll
        for (int rh = 0; rh < 2; rh++) {
            int tr = w * 32 + rh * 16 + lr;
            af[rh] = *reinterpret_cast<const bf16x8*>(ldsA + seg * 1024 + tr * 8);
        }
#pragma unroll
        for (int ct = 0; ct < 4; ct++) {
            bf16x8 bb = *reinterpret_cast<const bf16x8*>(ldsB + seg * 512 + (ct * 16 + lr) * 8);
#pragma unroll
            for (int rh = 0; rh < 2; rh++)
                acc[rh][ct] = __builtin_amdgcn_mfma_f32_16x16x32_bf16(af[rh], bb, acc[rh][ct], 0, 0, 0);
        }
        __syncthreads();
    }

#pragma unroll
    for (int ct = 0; ct < 4; ct++) {
        int col = n0 + ct * 16 + lr;
        float bo = b_out[col];
#pragma unroll
        for (int rh = 0; rh < 2; rh++) {
#pragma unroll
            for (int r = 0; r < 4; r++) {
                int row = rb + w * 32 + rh * 16 + seg * 4 + r;
                size_t idx = (size_t)row * 256 + col;
                float acs = tanhf(acc[rh][ct][r] + bo);
                float ng = (float)comb[(size_t)row * 512 + 256 + col];
                bf16x2 us = *reinterpret_cast<const bf16x2*>(ugsg + idx * 2);
                float ug = (float)us.x, sg = (float)us.y;
                float curr = ng + sg * acs;
                out[idx] = curr + ug * (hidden[idx] - curr);
            }
        }
    }
}

extern "C" void kernel_launch(void* const* d_in, const int* in_sizes, int n_in,
                              void* d_out, int out_size, void* d_ws, size_t ws_size,
                              hipStream_t stream) {
    const float* input_t = (const float*)d_in[0];
    const float* hidden  = (const float*)d_in[1];
    const float* w_ih    = (const float*)d_in[2];
    const float* b_ih    = (const float*)d_in[3];
    const float* w_hh    = (const float*)d_in[4];
    const float* b_hh    = (const float*)d_in[5];
    const float* w_out   = (const float*)d_in[6];
    const float* b_out   = (const float*)d_in[7];
    const float* memory  = (const float*)d_in[8];
    float* out = (float*)d_out;

    __bf16* base  = (__bf16*)d_ws;
    __bf16* AB    = base;
    __bf16* wihB  = base + E_AB;
    __bf16* whhB  = base + E_WIH;
    __bf16* woutB = base + E_WHH;
    __bf16* comb  = base + E_COMB;
    __bf16* ugsg  = base + E_UGSG;

    cast_kernel<<<4096, 256, 0, stream>>>(input_t, hidden, w_ih, w_hh, w_out, base);
    gates_gemm<<<dim3(8, 128), 256, 0, stream>>>(AB, wihB, whhB, b_ih, b_hh, comb, ugsg);
    attn_kernel<<<4096, 256, 0, stream>>>(input_t, memory, comb);
    out_gemm<<<dim3(4, 128), 256, 0, stream>>>(comb, woutB, b_out, ugsg, hidden, out);
}

// Round 3
// 209.504 us; speedup vs baseline: 1.2897x; 1.0362x over previous
//
#include <hip/hip_runtime.h>
#include <stdint.h>

#define B_N 16384
#define H_N 256
#define IN_W 258
#define GX_N 70
#define GY_N 70
#define SW_N 2
#define KK_N 25

typedef __bf16 bf16x8 __attribute__((ext_vector_type(8)));
typedef __bf16 bf16x4 __attribute__((ext_vector_type(4)));
typedef __bf16 bf16x2 __attribute__((ext_vector_type(2)));
typedef float f32x4 __attribute__((ext_vector_type(4)));

#define AS1 __attribute__((address_space(1)))
#define AS3 __attribute__((address_space(3)))

static __device__ __forceinline__ void gload16(const void* g, void* l) {
    __builtin_amdgcn_global_load_lds((const AS1 uint32_t*)g, (AS3 uint32_t*)l, 16, 0, 0);
}

// ---- ws layout (bf16 elements) ----
// AB    at 0        : [16384][512]  ([feat|hid])            16 MB
// wfull at 8388608  : [1024][512]   rows j=c*256+col, c in {r,i,s,n};
//                     k<256 -> wih[base_c+col][k], k>=256 -> whh[base_c+col][k-256]
//                     base_c = {0,256,768,512}
// woutB at 8912896  : [256][512]
// comb  at 9043968  : [16384][512]  ([mix|q])               16 MB
// ugsg  at 17432576 : [16384][256][2] (ug,sg interleaved)   16 MB
#define E_AB   8388608ULL
#define E_WF   8912896ULL
#define E_WOUT 9043968ULL
#define E_COMB 9043968ULL
#define E_UGSG 17432576ULL

__global__ __launch_bounds__(256) void cast_kernel(
    const float* __restrict__ in_t, const float* __restrict__ hid,
    const float* __restrict__ wih, const float* __restrict__ whh,
    const float* __restrict__ wout, __bf16* __restrict__ dst)
{
    size_t g = (size_t)blockIdx.x * blockDim.x + threadIdx.x;
    size_t stride = (size_t)gridDim.x * blockDim.x;
    for (size_t e = g * 4; e < E_WOUT; e += stride * 4) {
        const float* src;
        if (e < E_AB) {
            size_t row = e >> 9;
            size_t c = e & 511;
            src = (c < 256) ? (in_t + row * IN_W + c) : (hid + row * 256 + (c - 256));
        } else if (e < E_WF) {
            size_t off = e - E_AB;
            size_t j = off >> 9;       // 0..1023
            size_t k = off & 511;
            size_t c = j >> 8;         // 0..3
            size_t col = j & 255;
            size_t base = (c == 0) ? 0 : (c == 1) ? 256 : (c == 2) ? 768 : 512;
            const float* srcm = (k < 256) ? wih : whh;
            src = srcm + (base + col) * 256 + (k & 255);
        } else {
            src = wout + (e - E_WF);
        }
        bf16x4 o;
        o.x = (__bf16)src[0];
        o.y = (__bf16)src[1];
        o.z = (__bf16)src[2];
        o.w = (__bf16)src[3];
        *reinterpret_cast<bf16x4*>(dst + e) = o;
    }
}

// Fused gates GEMM, K=512 concat form.
// block = 128 rows x 32 hcols, 4 waves (each 32 rows x 32 cols).
// acc_s[c] (c=r,i,s) accumulate gi_c+gh_c over K=512; n-chunk split:
// acc_ni over k<256 (feat@wih_n), acc_nh over k>=256 (hid@whh_n).
// grid = (128 row-tiles, 8 h-tiles): id%8 = row%8 -> same-row tiles share XCD.
__global__ __launch_bounds__(256, 3) void gates_gemm(
    const __bf16* __restrict__ AB, const __bf16* __restrict__ wfull,
    const float* __restrict__ b_ih, const float* __restrict__ b_hh,
    __bf16* __restrict__ comb, __bf16* __restrict__ ugsg)
{
    __shared__ __bf16 ldsA[4096], ldsB[4096];
    const int t = threadIdx.x;
    const int lane = t & 63, w = t >> 6;
    const int lr = lane & 15, seg = lane >> 4;
    const int rb = blockIdx.x * 128;
    const int h0 = blockIdx.y * 32;

    // staging: 512 slots, seg-major (seg_s = u>>7, row = u&127); thread t owns u=t, u=t+256
    const int r_s = t & 127;
    const int s_lo = t >> 7;
    const __bf16* gA = AB + (size_t)(rb + r_s) * 512 + s_lo * 8;
    const int wr = ((r_s >> 5) << 8) + h0 + (r_s & 31);  // c*256 + h0 + col32
    const __bf16* gB = wfull + (size_t)wr * 512 + s_lo * 8;
    __bf16* lA = ldsA + t * 8;
    __bf16* lB = ldsB + t * 8;

    f32x4 acc_s[3][2][2], acc_ni[2][2], acc_nh[2][2];  // [..][hh][rh]
#pragma unroll
    for (int hh = 0; hh < 2; hh++)
#pragma unroll
        for (int rh = 0; rh < 2; rh++) {
#pragma unroll
            for (int c = 0; c < 3; c++) acc_s[c][hh][rh] = (f32x4){0.f, 0.f, 0.f, 0.f};
            acc_ni[hh][rh] = (f32x4){0.f, 0.f, 0.f, 0.f};
            acc_nh[hh][rh] = (f32x4){0.f, 0.f, 0.f, 0.f};
        }

#pragma unroll 1
    for (int half = 0; half < 2; half++) {
        for (int kt = half * 256; kt < half * 256 + 256; kt += 32) {
            gload16(gA + kt, lA);
            gload16(gA + kt + 16, lA + 2048);
            gload16(gB + kt, lB);
            gload16(gB + kt + 16, lB + 2048);
            __syncthreads();

            bf16x8 af[2];
#pragma unroll
            for (int rh = 0; rh < 2; rh++) {
                int tr = w * 32 + rh * 16 + lr;
                af[rh] = *reinterpret_cast<const bf16x8*>(ldsA + seg * 1024 + tr * 8);
            }
#pragma unroll
            for (int c = 0; c < 4; c++)
#pragma unroll
                for (int hh = 0; hh < 2; hh++) {
                    int br = c * 32 + hh * 16 + lr;
                    bf16x8 bb = *reinterpret_cast<const bf16x8*>(ldsB + seg * 1024 + br * 8);
#pragma unroll
                    for (int rh = 0; rh < 2; rh++) {
                        if (c < 3)
                            acc_s[c][hh][rh] = __builtin_amdgcn_mfma_f32_16x16x32_bf16(af[rh], bb, acc_s[c][hh][rh], 0, 0, 0);
                        else if (half == 0)
                            acc_ni[hh][rh] = __builtin_amdgcn_mfma_f32_16x16x32_bf16(af[rh], bb, acc_ni[hh][rh], 0, 0, 0);
                        else
                            acc_nh[hh][rh] = __builtin_amdgcn_mfma_f32_16x16x32_bf16(af[rh], bb, acc_nh[hh][rh], 0, 0, 0);
                    }
                }
            __syncthreads();
        }
    }

#pragma unroll
    for (int hh = 0; hh < 2; hh++) {
        int col = h0 + hh * 16 + lr;
        float br_ = b_ih[col] + b_hh[col];
        float bi_ = b_ih[col + 256] + b_hh[col + 256];
        float bs_ = b_ih[col + 768] + b_hh[col + 768];
        float bni = b_ih[col + 512];
        float bnh = b_hh[col + 512];
#pragma unroll
        for (int rh = 0; rh < 2; rh++) {
#pragma unroll
            for (int r = 0; r < 4; r++) {
                int row = rb + w * 32 + rh * 16 + seg * 4 + r;
                float sr = acc_s[0][hh][rh][r] + br_;
                float si = acc_s[1][hh][rh][r] + bi_;
                float ss = acc_s[2][hh][rh][r] + bs_;
                float ni = acc_ni[hh][rh][r] + bni;
                float nh = acc_nh[hh][rh][r] + bnh;
                float rg = 1.f / (1.f + __expf(-sr));
                float ug = 1.f / (1.f + __expf(-si));
                float sg = 1.f / (1.f + __expf(-ss));
                float ng = tanhf(ni + rg * nh);
                comb[(size_t)row * 512 + 256 + col] = (__bf16)ng;
                bf16x2 us;
                us.x = (__bf16)ug;
                us.y = (__bf16)sg;
                *reinterpret_cast<bf16x2*>(ugsg + ((size_t)row * 256 + col) * 2) = us;
            }
        }
    }
}

// Attention: one wave per row, online softmax, float4 per lane (h = 4*lane..4*lane+3).
__global__ __launch_bounds__(256) void attn_kernel(
    const float* __restrict__ in_t, const float* __restrict__ memory,
    __bf16* __restrict__ comb)
{
    const int w = threadIdx.x >> 6;
    const int lane = threadIdx.x & 63;
    const int b = blockIdx.x * 4 + w;
    const float* row_in = in_t + (size_t)b * IN_W;
    int gx = (int)row_in[256] + SW_N;
    int gy = (int)row_in[257] + SW_N;
    gx = min(max(gx, 0), GX_N - 1);
    gy = min(max(gy, 0), GY_N - 1);

    bf16x4 qb = *reinterpret_cast<const bf16x4*>(comb + (size_t)b * 512 + 256 + lane * 4);
    float q0 = (float)qb.x, q1 = (float)qb.y, q2 = (float)qb.z, q3 = (float)qb.w;

    float m = -INFINITY, d = 0.f;
    float o0 = 0.f, o1 = 0.f, o2 = 0.f, o3 = 0.f;
#pragma unroll
    for (int k = 0; k < KK_N; k++) {
        int i = k / 5, j = k % 5;
        int xi = min(max(gx + i - SW_N, 0), GX_N - 1);
        int yj = min(max(gy + j - SW_N, 0), GY_N - 1);
        const f32x4* cp = reinterpret_cast<const f32x4*>(memory + ((size_t)xi * GY_N + yj) * H_N);
        f32x4 v = cp[lane];
        float p = q0 * v.x + q1 * v.y + q2 * v.z + q3 * v.w;
        for (int off = 32; off; off >>= 1) p += __shfl_xor(p, off, 64);
        float a = (p == 0.f) ? -INFINITY : p;
        float mn = fmaxf(m, a);
        if (mn != -INFINITY) {
            float alpha = __expf(m - mn);   // m=-inf -> 0
            float e = __expf(a - mn);       // a=-inf -> 0
            d = d * alpha + e;
            o0 = o0 * alpha + e * v.x;
            o1 = o1 * alpha + e * v.y;
            o2 = o2 * alpha + e * v.z;
            o3 = o3 * alpha + e * v.w;
            m = mn;
        }
    }
    float inv = (d != 0.f) ? 1.f / d : 0.f;
    bf16x4 ob;
    ob.x = (__bf16)(o0 * inv);
    ob.y = (__bf16)(o1 * inv);
    ob.z = (__bf16)(o2 * inv);
    ob.w = (__bf16)(o3 * inv);
    *reinterpret_cast<bf16x4*>(comb + (size_t)b * 512 + lane * 4) = ob;
}

// Output GEMM (K=512) + tanh + final blend.
// grid = (128 row-tiles, 4 col-tiles): id%8 = row%8 -> XCD affinity.
__global__ __launch_bounds__(256, 4) void out_gemm(
    const __bf16* __restrict__ comb, const __bf16* __restrict__ woB,
    const float* __restrict__ b_out, const __bf16* __restrict__ ugsg,
    const float* __restrict__ hidden, float* __restrict__ out)
{
    __shared__ __bf16 ldsA[4096], ldsB[2048];
    const int t = threadIdx.x;
    const int lane = t & 63, w = t >> 6;
    const int lr = lane & 15, seg = lane >> 4;
    const int rb = blockIdx.x * 128;
    const int n0 = blockIdx.y * 64;

    const int rA = t & 127;
    const int sA = t >> 7;
    const __bf16* gA = comb + (size_t)(rb + rA) * 512 + sA * 8;
    __bf16* lA = ldsA + t * 8;
    const __bf16* gB = woB + (size_t)(n0 + (t & 63)) * 512 + (t >> 6) * 8;
    __bf16* lB = ldsB + t * 8;

    f32x4 acc[2][4];
#pragma unroll
    for (int rh = 0; rh < 2; rh++)
#pragma unroll
        for (int ct = 0; ct < 4; ct++) acc[rh][ct] = (f32x4){0.f, 0.f, 0.f, 0.f};

    for (int kt = 0; kt < 512; kt += 32) {
        gload16(gA + kt, lA);
        gload16(gA + kt + 16, lA + 2048);
        gload16(gB + kt, lB);
        __syncthreads();

        bf16x8 af[2];
#pragma unroll
        for (int rh = 0; rh < 2; rh++) {
            int tr = w * 32 + rh * 16 + lr;
            af[rh] = *reinterpret_cast<const bf16x8*>(ldsA + seg * 1024 + tr * 8);
        }
#pragma unroll
        for (int ct = 0; ct < 4; ct++) {
            bf16x8 bb = *reinterpret_cast<const bf16x8*>(ldsB + seg * 512 + (ct * 16 + lr) * 8);
#pragma unroll
            for (int rh = 0; rh < 2; rh++)
                acc[rh][ct] = __builtin_amdgcn_mfma_f32_16x16x32_bf16(af[rh], bb, acc[rh][ct], 0, 0, 0);
        }
        __syncthreads();
    }

#pragma unroll
    for (int ct = 0; ct < 4; ct++) {
        int col = n0 + ct * 16 + lr;
        float bo = b_out[col];
#pragma unroll
        for (int rh = 0; rh < 2; rh++) {
#pragma unroll
            for (int r = 0; r < 4; r++) {
                int row = rb + w * 32 + rh * 16 + seg * 4 + r;
                size_t idx = (size_t)row * 256 + col;
                float acs = tanhf(acc[rh][ct][r] + bo);
                float ng = (float)comb[(size_t)row * 512 + 256 + col];
                bf16x2 us = *reinterpret_cast<const bf16x2*>(ugsg + idx * 2);
                float ug = (float)us.x, sg = (float)us.y;
                float curr = ng + sg * acs;
                out[idx] = curr + ug * (hidden[idx] - curr);
            }
        }
    }
}

extern "C" void kernel_launch(void* const* d_in, const int* in_sizes, int n_in,
                              void* d_out, int out_size, void* d_ws, size_t ws_size,
                              hipStream_t stream) {
    const float* input_t = (const float*)d_in[0];
    const float* hidden  = (const float*)d_in[1];
    const float* w_ih    = (const float*)d_in[2];
    const float* b_ih    = (const float*)d_in[3];
    const float* w_hh    = (const float*)d_in[4];
    const float* b_hh    = (const float*)d_in[5];
    const float* w_out   = (const float*)d_in[6];
    const float* b_out   = (const float*)d_in[7];
    const float* memory  = (const float*)d_in[8];
    float* out = (float*)d_out;

    __bf16* base  = (__bf16*)d_ws;
    __bf16* AB    = base;
    __bf16* wfull = base + E_AB;
    __bf16* woutB = base + E_WF;
    __bf16* comb  = base + E_COMB;
    __bf16* ugsg  = base + E_UGSG;

    cast_kernel<<<4096, 256, 0, stream>>>(input_t, hidden, w_ih, w_hh, w_out, base);
    gates_gemm<<<dim3(128, 8), 256, 0, stream>>>(AB, wfull, b_ih, b_hh, comb, ugsg);
    attn_kernel<<<4096, 256, 0, stream>>>(input_t, memory, comb);
    out_gemm<<<dim3(128, 4), 256, 0, stream>>>(comb, woutB, b_out, ugsg, hidden, out);
}